// Round 5
// baseline (1249.196 us; speedup 1.0000x reference)
//
#include <hip/hip_runtime.h>
#include <cstdint>
#include <cstddef>

#define TSTEPS 500
#define BATCH  64
#define FEAT   256
#define HID    512
#define OUTD   128
#define ZROW   512   // all-zero padding row in wrecT/woutT

// ---------------- workspace layout (bytes) ----------------
#define XPROJ_OFF   ((size_t)0)
#define XPROJ_BYTES ((size_t)TSTEPS*BATCH*HID*4)
#define WRECT_OFF   (XPROJ_OFF + XPROJ_BYTES)
#define WRECT_BYTES ((size_t)(HID+1)*HID*4)
#define WOUTT_OFF   (WRECT_OFF + WRECT_BYTES)
#define WOUTT_BYTES ((size_t)(HID+1)*OUTD*4)
#define LISTS_OFF   (WOUTT_OFF + WOUTT_BYTES)
#define LISTS_BYTES ((size_t)TSTEPS*BATCH*HID*2)
#define CNTS_OFF    (LISTS_OFF + LISTS_BYTES)
#define CNTS_BYTES  ((size_t)TSTEPS*BATCH*4)

// ---------------- prep: transposes + zero pad rows ----------------
__global__ __launch_bounds__(256) void prep_kernel(const float* __restrict__ w_rec,
                                                   const float* __restrict__ w_out,
                                                   float* __restrict__ w_recT,
                                                   float* __restrict__ w_outT) {
    __shared__ float tile[32][33];
    int bid = blockIdx.x;
    const int tid = threadIdx.x;

    if (bid == 320) {                 // zero padding rows
        for (int i = tid; i < HID; i += 256) w_recT[(size_t)ZROW * HID + i] = 0.f;
        if (tid < OUTD) w_outT[(size_t)ZROW * OUTD + tid] = 0.f;
        return;
    }

    const float* src;
    float* dst;
    int scols, srows, tr, tc;
    if (bid < 256) {                  // w_rec: 512x512
        src = w_rec; dst = w_recT; srows = 512; scols = 512;
        tr = bid >> 4; tc = bid & 15;
    } else {                          // w_out: 128x512
        bid -= 256;
        src = w_out; dst = w_outT; srows = 128; scols = 512;
        tr = bid >> 4; tc = bid & 15;
    }
    const int c = tid & 31;
    const int r0 = tid >> 5;
#pragma unroll
    for (int p = 0; p < 4; ++p) {
        int r = p * 8 + r0;
        tile[r][c] = src[(size_t)(tr * 32 + r) * scols + tc * 32 + c];
    }
    __syncthreads();
#pragma unroll
    for (int p = 0; p < 4; ++p) {
        int r = p * 8 + r0;
        dst[(size_t)(tc * 32 + r) * srows + tr * 32 + c] = tile[c][r];
    }
}

// ---------------- x_proj GEMM: [32000x256] * [512x256]^T -> [32000x512] fp32 ----------------
__global__ __launch_bounds__(256) void xproj_kernel(const float* __restrict__ x,
                                                    const float* __restrict__ w_in,
                                                    float* __restrict__ xp) {
    __shared__ float At[32][132];
    __shared__ float Bt[32][132];
    const int tid = threadIdx.x;
    const int bm = blockIdx.x % 250;
    const int bn = blockIdx.x / 250;
    const int m0 = bm * 128, n0 = bn * 128;
    const int tx = tid & 15, ty = tid >> 4;
    const int lr = tid >> 3;
    const int lc = (tid & 7) << 2;

    float acc[8][8];
#pragma unroll
    for (int i = 0; i < 8; ++i)
#pragma unroll
        for (int j = 0; j < 8; ++j) acc[i][j] = 0.f;

    for (int k0 = 0; k0 < FEAT; k0 += 32) {
#pragma unroll
        for (int rr = 0; rr < 128; rr += 32) {
            float4 av = *reinterpret_cast<const float4*>(x + (size_t)(m0 + lr + rr) * FEAT + k0 + lc);
            At[lc + 0][lr + rr] = av.x; At[lc + 1][lr + rr] = av.y;
            At[lc + 2][lr + rr] = av.z; At[lc + 3][lr + rr] = av.w;
            float4 bv = *reinterpret_cast<const float4*>(w_in + (size_t)(n0 + lr + rr) * FEAT + k0 + lc);
            Bt[lc + 0][lr + rr] = bv.x; Bt[lc + 1][lr + rr] = bv.y;
            Bt[lc + 2][lr + rr] = bv.z; Bt[lc + 3][lr + rr] = bv.w;
        }
        __syncthreads();
#pragma unroll
        for (int kk = 0; kk < 32; ++kk) {
            float a[8], bb[8];
            *reinterpret_cast<float4*>(&a[0]) = *reinterpret_cast<const float4*>(&At[kk][ty * 8]);
            *reinterpret_cast<float4*>(&a[4]) = *reinterpret_cast<const float4*>(&At[kk][ty * 8 + 4]);
            *reinterpret_cast<float4*>(&bb[0]) = *reinterpret_cast<const float4*>(&Bt[kk][tx * 8]);
            *reinterpret_cast<float4*>(&bb[4]) = *reinterpret_cast<const float4*>(&Bt[kk][tx * 8 + 4]);
#pragma unroll
            for (int i = 0; i < 8; ++i)
#pragma unroll
                for (int j = 0; j < 8; ++j)
                    acc[i][j] = fmaf(a[i], bb[j], acc[i][j]);
        }
        __syncthreads();
    }
#pragma unroll
    for (int i = 0; i < 8; ++i) {
        float* dst = xp + (size_t)(m0 + ty * 8 + i) * HID + n0 + tx * 8;
        *reinterpret_cast<float4*>(dst)     = make_float4(acc[i][0], acc[i][1], acc[i][2], acc[i][3]);
        *reinterpret_cast<float4*>(dst + 4) = make_float4(acc[i][4], acc[i][5], acc[i][6], acc[i][7]);
    }
}

// ---------------- recurrent LIF-AdEx scan: one block (512 thr) per batch element ----------------
// LDS spike list holds BYTE OFFSETS into wrecT (h<<11); padded to x64 with ZROW.
// Gather uses inline-asm global_load_dword so all 64 loads of a chunk stay in flight
// (round-4 lesson: pure C++ batching is collapsed by the register-pressure scheduler).
__global__ __launch_bounds__(512, 1) void scan_kernel(const float* __restrict__ xproj,
                                                      const float* __restrict__ wrecT,  // [513][512]
                                                      unsigned short* __restrict__ glists,
                                                      int* __restrict__ gcnts,
                                                      float* __restrict__ st_out) {
    const int b = blockIdx.x;
    const int tid = threadIdx.x;           // h
    const int lane = tid & 63;
    const int wvi = tid >> 6;              // 0..7
    __shared__ unsigned long long zw[8];
    __shared__ int ilist[2][HID];

    float v = 0.f, cur = 0.f, ad = 0.f, zf = 0.f;
    int cntp = 0, rb = 0;
    const unsigned long long lm = (1ULL << lane) - 1ULL;
    const unsigned tid4 = (unsigned)tid << 2;
    const float* wbase = wrecT;

    const float* xpp = xproj + (size_t)b * HID + tid;
    float xpn = xpp[0];

    for (int t = 0; t < TSTEPS; ++t) {
        const float xp = xpn;
        if (t + 1 < TSTEPS) xpn = xpp[(size_t)(t + 1) * BATCH * HID];

        // ---- recurrent gather: 64 loads in flight per chunk (single latency exposure) ----
        float r = 0.f;
        const int* lst = ilist[rb];
        for (int s0 = 0; s0 < cntp; s0 += 64) {
            unsigned off[64];
#pragma unroll
            for (int q = 0; q < 16; ++q) {
                int4 w = *reinterpret_cast<const int4*>(lst + s0 + 4 * q);
                off[4*q+0] = (unsigned)w.x + tid4;
                off[4*q+1] = (unsigned)w.y + tid4;
                off[4*q+2] = (unsigned)w.z + tid4;
                off[4*q+3] = (unsigned)w.w + tid4;
            }
            float f[64];
#pragma unroll
            for (int j = 0; j < 64; ++j)
                asm volatile("global_load_dword %0, %1, %2"
                             : "=v"(f[j]) : "v"(off[j]), "s"(wbase));
            asm volatile("s_waitcnt vmcnt(0)" ::: "memory");
            __builtin_amdgcn_sched_barrier(0);   // rule #18: keep consumers after the waitcnt
            float A = 0.f, B = 0.f, C = 0.f, D = 0.f;
#pragma unroll
            for (int j = 0; j < 64; j += 4) { A += f[j]; B += f[j+1]; C += f[j+2]; D += f[j+3]; }
            r += (A + B) + (C + D);
        }

        // ---- LIF-AdEx element-wise update ----
        float vd = v + 0.1f * ((((0.f - v) + 0.5f * expf((v - 1.f) * 2.f)) + cur) - ad);
        float id = cur - 0.2f * cur;
        float aD = ad + 0.002f * (4.f * v - ad);
        bool z = (vd - 1.f) > 0.f;
        v = z ? 0.f : vd;
        cur = id + xp + r;
        ad = aD + (z ? 0.02f : 0.f);
        zf = z ? 1.f : 0.f;

        // ---- build next spike list ----
        unsigned long long m = __ballot(z);
        if (lane == 0) zw[wvi] = m;
        __syncthreads();                       // A: zw visible; all gathers from ilist[rb] done
        int off2 = 0, tot = 0;
#pragma unroll
        for (int ww = 0; ww < 8; ++ww) {
            int p = __popcll(zw[ww]);
            if (ww < wvi) off2 += p;
            tot += p;
        }
        const int wb = rb ^ 1;
        if (z) ilist[wb][off2 + __popcll(m & lm)] = tid << 11;
        const int pad = (tot + 63) & ~63;
        if (tid >= tot && tid < pad) ilist[wb][tid] = ZROW << 11;
        __syncthreads();                       // B: ilist[wb] complete
        // export step-t spike list (off critical path; store doesn't block)
        if (tid < pad)
            glists[((size_t)t * BATCH + b) * HID + tid] =
                (unsigned short)(((unsigned)ilist[wb][tid]) >> 11);
        if (tid == 0) gcnts[t * BATCH + b] = pad;
        cntp = pad;
        rb = wb;
    }

    // final states: z, v, i, a  each [64][512]
    const size_t base = (size_t)b * HID + tid;
    st_out[0 * (size_t)BATCH * HID + base] = zf;
    st_out[1 * (size_t)BATCH * HID + base] = v;
    st_out[2 * (size_t)BATCH * HID + base] = cur;
    st_out[3 * (size_t)BATCH * HID + base] = ad;
}

// ---------------- output projection + exponential filter ----------------
// 16 t-chunks x 64 batch = 1024 blocks; 48-step halo (0.7769^48 ~ 5.5e-6).
__global__ __launch_bounds__(128) void out_kernel(const unsigned short* __restrict__ lists,
                                                  const int* __restrict__ cnts,
                                                  const float* __restrict__ woutT,  // [513][128]
                                                  const float* __restrict__ b_out,
                                                  float* __restrict__ out) {
    const int bid = blockIdx.x;
    const int b = bid & 63;
    const int chunk = bid >> 6;            // 0..15
    const int o = threadIdx.x;
    const unsigned o4 = (unsigned)o << 2;
    const int t0 = chunk * 32;
    const int tstart = (t0 >= 48) ? (t0 - 48) : 0;
    int tend = t0 + 32; if (tend > TSTEPS) tend = TSTEPS;
    const float bo = b_out[o];
    const float cf = 0.2231435511314f;
    const char* wbase = (const char*)woutT;
    float y = 0.f;
    for (int t = tstart; t < tend; ++t) {
        const int cnt = cnts[t * BATCH + b];           // padded to x64
        const unsigned short* lp = lists + ((size_t)t * BATCH + b) * HID;
        float lin = bo;
        for (int s0 = 0; s0 < cnt; s0 += 32) {
            uint4 u[4];
#pragma unroll
            for (int q = 0; q < 4; ++q) u[q] = *reinterpret_cast<const uint4*>(lp + s0 + 8 * q);
            float f[32];
#pragma unroll
            for (int q = 0; q < 4; ++q) {
                unsigned a0 = u[q].x, a1 = u[q].y, a2 = u[q].z, a3 = u[q].w;
                f[8*q+0] = *reinterpret_cast<const float*>(wbase + (((a0 & 0xffffu) << 9) + o4));
                f[8*q+1] = *reinterpret_cast<const float*>(wbase + (((a0 >> 16) << 9) + o4));
                f[8*q+2] = *reinterpret_cast<const float*>(wbase + (((a1 & 0xffffu) << 9) + o4));
                f[8*q+3] = *reinterpret_cast<const float*>(wbase + (((a1 >> 16) << 9) + o4));
                f[8*q+4] = *reinterpret_cast<const float*>(wbase + (((a2 & 0xffffu) << 9) + o4));
                f[8*q+5] = *reinterpret_cast<const float*>(wbase + (((a2 >> 16) << 9) + o4));
                f[8*q+6] = *reinterpret_cast<const float*>(wbase + (((a3 & 0xffffu) << 9) + o4));
                f[8*q+7] = *reinterpret_cast<const float*>(wbase + (((a3 >> 16) << 9) + o4));
            }
            __builtin_amdgcn_sched_barrier(0);
            float A = 0.f, Bs = 0.f, C = 0.f, D = 0.f;
#pragma unroll
            for (int j = 0; j < 32; j += 4) { A += f[j]; Bs += f[j+1]; C += f[j+2]; D += f[j+3]; }
            lin += (A + Bs) + (C + D);
        }
        y = y + cf * (lin - y);
        if (t >= t0) out[((size_t)t * BATCH + b) * OUTD + o] = y;
    }
}

// ---------------- launcher ----------------
extern "C" void kernel_launch(void* const* d_in, const int* in_sizes, int n_in,
                              void* d_out, int out_size, void* d_ws, size_t ws_size,
                              hipStream_t stream) {
    const float* x     = (const float*)d_in[0];
    const float* w_in  = (const float*)d_in[1];
    const float* w_rec = (const float*)d_in[2];
    const float* w_out = (const float*)d_in[3];
    const float* b_out = (const float*)d_in[4];
    float* out = (float*)d_out;

    char* ws = (char*)d_ws;
    float* xproj          = (float*)(ws + XPROJ_OFF);
    float* wrecT          = (float*)(ws + WRECT_OFF);
    float* woutT          = (float*)(ws + WOUTT_OFF);
    unsigned short* lists = (unsigned short*)(ws + LISTS_OFF);
    int* cnts             = (int*)(ws + CNTS_OFF);
    float* st_out = out + (size_t)TSTEPS * BATCH * OUTD;

    prep_kernel<<<321, 256, 0, stream>>>(w_rec, w_out, wrecT, woutT);
    xproj_kernel<<<1000, 256, 0, stream>>>(x, w_in, xproj);
    scan_kernel<<<64, 512, 0, stream>>>(xproj, wrecT, lists, cnts, st_out);
    out_kernel<<<1024, 128, 0, stream>>>(lists, cnts, woutT, b_out, out);
}

// Round 6
// 1128.669 us; speedup vs baseline: 1.1068x; 1.1068x over previous
//
#include <hip/hip_runtime.h>
#include <cstdint>
#include <cstddef>

#define TSTEPS 500
#define BATCH  64
#define FEAT   256
#define HID    512
#define OUTD   128
#define ZROW   512   // all-zero padding row in wrecT/woutT

// ---------------- workspace layout (bytes) ----------------
#define XPROJ_OFF   ((size_t)0)
#define XPROJ_BYTES ((size_t)TSTEPS*BATCH*HID*4)
#define WRECT_OFF   (XPROJ_OFF + XPROJ_BYTES)
#define WRECT_BYTES ((size_t)(HID+1)*HID*4)
#define WOUTT_OFF   (WRECT_OFF + WRECT_BYTES)
#define WOUTT_BYTES ((size_t)(HID+1)*OUTD*4)
#define LISTS_OFF   (WOUTT_OFF + WOUTT_BYTES)
#define LISTS_BYTES ((size_t)TSTEPS*BATCH*HID*2)
#define CNTS_OFF    (LISTS_OFF + LISTS_BYTES)
#define CNTS_BYTES  ((size_t)TSTEPS*BATCH*4)

// ---------------- prep: transposes + zero pad rows ----------------
__global__ __launch_bounds__(256) void prep_kernel(const float* __restrict__ w_rec,
                                                   const float* __restrict__ w_out,
                                                   float* __restrict__ w_recT,
                                                   float* __restrict__ w_outT) {
    __shared__ float tile[32][33];
    int bid = blockIdx.x;
    const int tid = threadIdx.x;

    if (bid == 320) {                 // zero padding rows
        for (int i = tid; i < HID; i += 256) w_recT[(size_t)ZROW * HID + i] = 0.f;
        if (tid < OUTD) w_outT[(size_t)ZROW * OUTD + tid] = 0.f;
        return;
    }

    const float* src;
    float* dst;
    int scols, srows, tr, tc;
    if (bid < 256) {                  // w_rec: 512x512
        src = w_rec; dst = w_recT; srows = 512; scols = 512;
        tr = bid >> 4; tc = bid & 15;
    } else {                          // w_out: 128x512
        bid -= 256;
        src = w_out; dst = w_outT; srows = 128; scols = 512;
        tr = bid >> 4; tc = bid & 15;
    }
    const int c = tid & 31;
    const int r0 = tid >> 5;
#pragma unroll
    for (int p = 0; p < 4; ++p) {
        int r = p * 8 + r0;
        tile[r][c] = src[(size_t)(tr * 32 + r) * scols + tc * 32 + c];
    }
    __syncthreads();
#pragma unroll
    for (int p = 0; p < 4; ++p) {
        int r = p * 8 + r0;
        dst[(size_t)(tc * 32 + r) * srows + tr * 32 + c] = tile[c][r];
    }
}

// ---------------- x_proj GEMM: [32000x256] * [512x256]^T -> [32000x512] fp32 ----------------
__global__ __launch_bounds__(256) void xproj_kernel(const float* __restrict__ x,
                                                    const float* __restrict__ w_in,
                                                    float* __restrict__ xp) {
    __shared__ float At[32][132];
    __shared__ float Bt[32][132];
    const int tid = threadIdx.x;
    const int bm = blockIdx.x % 250;
    const int bn = blockIdx.x / 250;
    const int m0 = bm * 128, n0 = bn * 128;
    const int tx = tid & 15, ty = tid >> 4;
    const int lr = tid >> 3;
    const int lc = (tid & 7) << 2;

    float acc[8][8];
#pragma unroll
    for (int i = 0; i < 8; ++i)
#pragma unroll
        for (int j = 0; j < 8; ++j) acc[i][j] = 0.f;

    for (int k0 = 0; k0 < FEAT; k0 += 32) {
#pragma unroll
        for (int rr = 0; rr < 128; rr += 32) {
            float4 av = *reinterpret_cast<const float4*>(x + (size_t)(m0 + lr + rr) * FEAT + k0 + lc);
            At[lc + 0][lr + rr] = av.x; At[lc + 1][lr + rr] = av.y;
            At[lc + 2][lr + rr] = av.z; At[lc + 3][lr + rr] = av.w;
            float4 bv = *reinterpret_cast<const float4*>(w_in + (size_t)(n0 + lr + rr) * FEAT + k0 + lc);
            Bt[lc + 0][lr + rr] = bv.x; Bt[lc + 1][lr + rr] = bv.y;
            Bt[lc + 2][lr + rr] = bv.z; Bt[lc + 3][lr + rr] = bv.w;
        }
        __syncthreads();
#pragma unroll
        for (int kk = 0; kk < 32; ++kk) {
            float a[8], bb[8];
            *reinterpret_cast<float4*>(&a[0]) = *reinterpret_cast<const float4*>(&At[kk][ty * 8]);
            *reinterpret_cast<float4*>(&a[4]) = *reinterpret_cast<const float4*>(&At[kk][ty * 8 + 4]);
            *reinterpret_cast<float4*>(&bb[0]) = *reinterpret_cast<const float4*>(&Bt[kk][tx * 8]);
            *reinterpret_cast<float4*>(&bb[4]) = *reinterpret_cast<const float4*>(&Bt[kk][tx * 8 + 4]);
#pragma unroll
            for (int i = 0; i < 8; ++i)
#pragma unroll
                for (int j = 0; j < 8; ++j)
                    acc[i][j] = fmaf(a[i], bb[j], acc[i][j]);
        }
        __syncthreads();
    }
#pragma unroll
    for (int i = 0; i < 8; ++i) {
        float* dst = xp + (size_t)(m0 + ty * 8 + i) * HID + n0 + tx * 8;
        *reinterpret_cast<float4*>(dst)     = make_float4(acc[i][0], acc[i][1], acc[i][2], acc[i][3]);
        *reinterpret_cast<float4*>(dst + 4) = make_float4(acc[i][4], acc[i][5], acc[i][6], acc[i][7]);
    }
}

// ---------------- recurrent LIF-AdEx scan: one block (512 thr) per batch element ----------------
// LDS spike list holds BYTE OFFSETS into wrecT (h<<11); padded to x64 with ZROW.
// amdgpu_waves_per_eu(2,2): one 512-thr block/CU = exactly 2 waves/EU, so raise the
// VGPR budget to 256 — otherwise the pre-RA scheduler targets 8 waves/EU (~64 VGPR)
// and collapses the 64-deep gather batch into ~8-deep WAR chains (r2/r4/r5 evidence).
__global__ __launch_bounds__(512)
__attribute__((amdgpu_waves_per_eu(2, 2)))
void scan_kernel(const float* __restrict__ xproj,
                 const float* __restrict__ wrecT,  // [513][512]
                 unsigned short* __restrict__ glists,
                 int* __restrict__ gcnts,
                 float* __restrict__ st_out) {
    const int b = blockIdx.x;
    const int tid = threadIdx.x;           // h
    const int lane = tid & 63;
    const int wvi = tid >> 6;              // 0..7
    __shared__ unsigned long long zw[8];
    __shared__ int ilist[2][HID];

    float v = 0.f, cur = 0.f, ad = 0.f, zf = 0.f;
    int cntp = 0, rb = 0;
    const unsigned long long lm = (1ULL << lane) - 1ULL;
    const unsigned tid4 = (unsigned)tid << 2;
    const char* wbase = (const char*)wrecT;

    const float* xpp = xproj + (size_t)b * HID + tid;
    float xpn = xpp[0];

    for (int t = 0; t < TSTEPS; ++t) {
        const float xp = xpn;
        if (t + 1 < TSTEPS) xpn = xpp[(size_t)(t + 1) * BATCH * HID];

        // ---- recurrent gather: 64 loads in flight per chunk (single latency exposure) ----
        float r = 0.f;
        const int* lst = ilist[rb];
        for (int s0 = 0; s0 < cntp; s0 += 64) {
            float f[64];
#pragma unroll
            for (int q = 0; q < 16; ++q) {
                int4 w = *reinterpret_cast<const int4*>(lst + s0 + 4 * q);
                f[4*q+0] = *reinterpret_cast<const float*>(wbase + (unsigned)((unsigned)w.x + tid4));
                f[4*q+1] = *reinterpret_cast<const float*>(wbase + (unsigned)((unsigned)w.y + tid4));
                f[4*q+2] = *reinterpret_cast<const float*>(wbase + (unsigned)((unsigned)w.z + tid4));
                f[4*q+3] = *reinterpret_cast<const float*>(wbase + (unsigned)((unsigned)w.w + tid4));
            }
            __builtin_amdgcn_sched_barrier(0);   // keep all 64 loads issued before consumption
            float A = 0.f, B = 0.f, C = 0.f, D = 0.f;
#pragma unroll
            for (int j = 0; j < 64; j += 4) { A += f[j]; B += f[j+1]; C += f[j+2]; D += f[j+3]; }
            r += (A + B) + (C + D);
        }

        // ---- LIF-AdEx element-wise update ----
        float vd = v + 0.1f * ((((0.f - v) + 0.5f * expf((v - 1.f) * 2.f)) + cur) - ad);
        float id = cur - 0.2f * cur;
        float aD = ad + 0.002f * (4.f * v - ad);
        bool z = (vd - 1.f) > 0.f;
        v = z ? 0.f : vd;
        cur = id + xp + r;
        ad = aD + (z ? 0.02f : 0.f);
        zf = z ? 1.f : 0.f;

        // ---- build next spike list ----
        unsigned long long m = __ballot(z);
        if (lane == 0) zw[wvi] = m;
        __syncthreads();                       // A: zw visible; all gathers from ilist[rb] done
        int off2 = 0, tot = 0;
#pragma unroll
        for (int ww = 0; ww < 8; ++ww) {
            int p = __popcll(zw[ww]);
            if (ww < wvi) off2 += p;
            tot += p;
        }
        const int wb = rb ^ 1;
        if (z) ilist[wb][off2 + __popcll(m & lm)] = tid << 11;
        const int pad = (tot + 63) & ~63;
        if (tid >= tot && tid < pad) ilist[wb][tid] = ZROW << 11;
        __syncthreads();                       // B: ilist[wb] complete
        // export step-t spike list (off critical path; store doesn't block)
        if (tid < pad)
            glists[((size_t)t * BATCH + b) * HID + tid] =
                (unsigned short)(((unsigned)ilist[wb][tid]) >> 11);
        if (tid == 0) gcnts[t * BATCH + b] = pad;
        cntp = pad;
        rb = wb;
    }

    // final states: z, v, i, a  each [64][512]
    const size_t base = (size_t)b * HID + tid;
    st_out[0 * (size_t)BATCH * HID + base] = zf;
    st_out[1 * (size_t)BATCH * HID + base] = v;
    st_out[2 * (size_t)BATCH * HID + base] = cur;
    st_out[3 * (size_t)BATCH * HID + base] = ad;
}

// ---------------- output projection + exponential filter ----------------
// 16 t-chunks x 64 batch = 1024 blocks; 48-step halo (0.7769^48 ~ 5.5e-6).
__global__ __launch_bounds__(128) void out_kernel(const unsigned short* __restrict__ lists,
                                                  const int* __restrict__ cnts,
                                                  const float* __restrict__ woutT,  // [513][128]
                                                  const float* __restrict__ b_out,
                                                  float* __restrict__ out) {
    const int bid = blockIdx.x;
    const int b = bid & 63;
    const int chunk = bid >> 6;            // 0..15
    const int o = threadIdx.x;
    const unsigned o4 = (unsigned)o << 2;
    const int t0 = chunk * 32;
    const int tstart = (t0 >= 48) ? (t0 - 48) : 0;
    int tend = t0 + 32; if (tend > TSTEPS) tend = TSTEPS;
    const float bo = b_out[o];
    const float cf = 0.2231435511314f;
    const char* wbase = (const char*)woutT;
    float y = 0.f;
    for (int t = tstart; t < tend; ++t) {
        const int cnt = cnts[t * BATCH + b];           // padded to x64
        const unsigned short* lp = lists + ((size_t)t * BATCH + b) * HID;
        float lin = bo;
        for (int s0 = 0; s0 < cnt; s0 += 32) {
            uint4 u[4];
#pragma unroll
            for (int q = 0; q < 4; ++q) u[q] = *reinterpret_cast<const uint4*>(lp + s0 + 8 * q);
            float f[32];
#pragma unroll
            for (int q = 0; q < 4; ++q) {
                unsigned a0 = u[q].x, a1 = u[q].y, a2 = u[q].z, a3 = u[q].w;
                f[8*q+0] = *reinterpret_cast<const float*>(wbase + (((a0 & 0xffffu) << 9) + o4));
                f[8*q+1] = *reinterpret_cast<const float*>(wbase + (((a0 >> 16) << 9) + o4));
                f[8*q+2] = *reinterpret_cast<const float*>(wbase + (((a1 & 0xffffu) << 9) + o4));
                f[8*q+3] = *reinterpret_cast<const float*>(wbase + (((a1 >> 16) << 9) + o4));
                f[8*q+4] = *reinterpret_cast<const float*>(wbase + (((a2 & 0xffffu) << 9) + o4));
                f[8*q+5] = *reinterpret_cast<const float*>(wbase + (((a2 >> 16) << 9) + o4));
                f[8*q+6] = *reinterpret_cast<const float*>(wbase + (((a3 & 0xffffu) << 9) + o4));
                f[8*q+7] = *reinterpret_cast<const float*>(wbase + (((a3 >> 16) << 9) + o4));
            }
            __builtin_amdgcn_sched_barrier(0);
            float A = 0.f, Bs = 0.f, C = 0.f, D = 0.f;
#pragma unroll
            for (int j = 0; j < 32; j += 4) { A += f[j]; Bs += f[j+1]; C += f[j+2]; D += f[j+3]; }
            lin += (A + Bs) + (C + D);
        }
        y = y + cf * (lin - y);
        if (t >= t0) out[((size_t)t * BATCH + b) * OUTD + o] = y;
    }
}

// ---------------- launcher ----------------
extern "C" void kernel_launch(void* const* d_in, const int* in_sizes, int n_in,
                              void* d_out, int out_size, void* d_ws, size_t ws_size,
                              hipStream_t stream) {
    const float* x     = (const float*)d_in[0];
    const float* w_in  = (const float*)d_in[1];
    const float* w_rec = (const float*)d_in[2];
    const float* w_out = (const float*)d_in[3];
    const float* b_out = (const float*)d_in[4];
    float* out = (float*)d_out;

    char* ws = (char*)d_ws;
    float* xproj          = (float*)(ws + XPROJ_OFF);
    float* wrecT          = (float*)(ws + WRECT_OFF);
    float* woutT          = (float*)(ws + WOUTT_OFF);
    unsigned short* lists = (unsigned short*)(ws + LISTS_OFF);
    int* cnts             = (int*)(ws + CNTS_OFF);
    float* st_out = out + (size_t)TSTEPS * BATCH * OUTD;

    prep_kernel<<<321, 256, 0, stream>>>(w_rec, w_out, wrecT, woutT);
    xproj_kernel<<<1000, 256, 0, stream>>>(x, w_in, xproj);
    scan_kernel<<<64, 512, 0, stream>>>(xproj, wrecT, lists, cnts, st_out);
    out_kernel<<<1024, 128, 0, stream>>>(lists, cnts, woutT, b_out, out);
}

// Round 7
// 878.370 us; speedup vs baseline: 1.4222x; 1.2850x over previous
//
#include <hip/hip_runtime.h>
#include <cstdint>
#include <cstddef>

#define TSTEPS 500
#define BATCH  64
#define FEAT   256
#define HID    512
#define OUTD   128
#define ZROW   512   // all-zero padding row in wrecT/woutT

// ---------------- workspace layout (bytes) ----------------
#define XPROJ_OFF   ((size_t)0)
#define XPROJ_BYTES ((size_t)TSTEPS*BATCH*HID*4)
#define WRECT_OFF   (XPROJ_OFF + XPROJ_BYTES)
#define WRECT_BYTES ((size_t)(HID+1)*HID*4)
#define WOUTT_OFF   (WRECT_OFF + WRECT_BYTES)
#define WOUTT_BYTES ((size_t)(HID+1)*OUTD*4)
#define LISTS_OFF   (WOUTT_OFF + WOUTT_BYTES)
#define LISTS_BYTES ((size_t)TSTEPS*BATCH*HID*2)
#define CNTS_OFF    (LISTS_OFF + LISTS_BYTES)
#define CNTS_BYTES  ((size_t)TSTEPS*BATCH*4)

// ---------------- prep: transposes + zero pad rows ----------------
__global__ __launch_bounds__(256) void prep_kernel(const float* __restrict__ w_rec,
                                                   const float* __restrict__ w_out,
                                                   float* __restrict__ w_recT,
                                                   float* __restrict__ w_outT) {
    __shared__ float tile[32][33];
    int bid = blockIdx.x;
    const int tid = threadIdx.x;

    if (bid == 320) {                 // zero padding rows
        for (int i = tid; i < HID; i += 256) w_recT[(size_t)ZROW * HID + i] = 0.f;
        if (tid < OUTD) w_outT[(size_t)ZROW * OUTD + tid] = 0.f;
        return;
    }

    const float* src;
    float* dst;
    int scols, srows, tr, tc;
    if (bid < 256) {                  // w_rec: 512x512
        src = w_rec; dst = w_recT; srows = 512; scols = 512;
        tr = bid >> 4; tc = bid & 15;
    } else {                          // w_out: 128x512
        bid -= 256;
        src = w_out; dst = w_outT; srows = 128; scols = 512;
        tr = bid >> 4; tc = bid & 15;
    }
    const int c = tid & 31;
    const int r0 = tid >> 5;
#pragma unroll
    for (int p = 0; p < 4; ++p) {
        int r = p * 8 + r0;
        tile[r][c] = src[(size_t)(tr * 32 + r) * scols + tc * 32 + c];
    }
    __syncthreads();
#pragma unroll
    for (int p = 0; p < 4; ++p) {
        int r = p * 8 + r0;
        dst[(size_t)(tc * 32 + r) * srows + tr * 32 + c] = tile[c][r];
    }
}

// ---------------- x_proj GEMM: [32000x256] * [512x256]^T -> [32000x512] fp32 ----------------
__global__ __launch_bounds__(256) void xproj_kernel(const float* __restrict__ x,
                                                    const float* __restrict__ w_in,
                                                    float* __restrict__ xp) {
    __shared__ float At[32][132];
    __shared__ float Bt[32][132];
    const int tid = threadIdx.x;
    const int bm = blockIdx.x % 250;
    const int bn = blockIdx.x / 250;
    const int m0 = bm * 128, n0 = bn * 128;
    const int tx = tid & 15, ty = tid >> 4;
    const int lr = tid >> 3;
    const int lc = (tid & 7) << 2;

    float acc[8][8];
#pragma unroll
    for (int i = 0; i < 8; ++i)
#pragma unroll
        for (int j = 0; j < 8; ++j) acc[i][j] = 0.f;

    for (int k0 = 0; k0 < FEAT; k0 += 32) {
#pragma unroll
        for (int rr = 0; rr < 128; rr += 32) {
            float4 av = *reinterpret_cast<const float4*>(x + (size_t)(m0 + lr + rr) * FEAT + k0 + lc);
            At[lc + 0][lr + rr] = av.x; At[lc + 1][lr + rr] = av.y;
            At[lc + 2][lr + rr] = av.z; At[lc + 3][lr + rr] = av.w;
            float4 bv = *reinterpret_cast<const float4*>(w_in + (size_t)(n0 + lr + rr) * FEAT + k0 + lc);
            Bt[lc + 0][lr + rr] = bv.x; Bt[lc + 1][lr + rr] = bv.y;
            Bt[lc + 2][lr + rr] = bv.z; Bt[lc + 3][lr + rr] = bv.w;
        }
        __syncthreads();
#pragma unroll
        for (int kk = 0; kk < 32; ++kk) {
            float a[8], bb[8];
            *reinterpret_cast<float4*>(&a[0]) = *reinterpret_cast<const float4*>(&At[kk][ty * 8]);
            *reinterpret_cast<float4*>(&a[4]) = *reinterpret_cast<const float4*>(&At[kk][ty * 8 + 4]);
            *reinterpret_cast<float4*>(&bb[0]) = *reinterpret_cast<const float4*>(&Bt[kk][tx * 8]);
            *reinterpret_cast<float4*>(&bb[4]) = *reinterpret_cast<const float4*>(&Bt[kk][tx * 8 + 4]);
#pragma unroll
            for (int i = 0; i < 8; ++i)
#pragma unroll
                for (int j = 0; j < 8; ++j)
                    acc[i][j] = fmaf(a[i], bb[j], acc[i][j]);
        }
        __syncthreads();
    }
#pragma unroll
    for (int i = 0; i < 8; ++i) {
        float* dst = xp + (size_t)(m0 + ty * 8 + i) * HID + n0 + tx * 8;
        *reinterpret_cast<float4*>(dst)     = make_float4(acc[i][0], acc[i][1], acc[i][2], acc[i][3]);
        *reinterpret_cast<float4*>(dst + 4) = make_float4(acc[i][4], acc[i][5], acc[i][6], acc[i][7]);
    }
}

// ---------------- recurrent LIF-AdEx scan: one block (512 thr) per batch element ----------------
// Gather restructure (r7): 4 rows per group, each thread loads float4 (4 cols of one row):
// rows cost 2 wave-instrs instead of 8 — tests instr-bound vs byte-bound return path.
// Tail rows masked to ZROW in-register (no stored padding, no padded exports).
// Cross-thread reduce: acc4 -> LDS red -> 4 stride-512 float reads (conflict-free).
__global__ __launch_bounds__(512)
__attribute__((amdgpu_waves_per_eu(2, 2)))
void scan_kernel(const float* __restrict__ xproj,
                 const float* __restrict__ wrecT,  // [513][512]
                 unsigned short* __restrict__ glists,
                 int* __restrict__ gcnts,
                 float* __restrict__ st_out) {
    const int b = blockIdx.x;
    const int tid = threadIdx.x;           // h
    const int lane = tid & 63;
    const int wvi = tid >> 6;              // 0..7
    __shared__ unsigned long long zw[8];
    __shared__ int ilist[2][HID];
    __shared__ float4 red4[HID];

    float v = 0.f, cur = 0.f, ad = 0.f, zf = 0.f;
    int cntp = 0, rb = 0;
    const unsigned long long lm = (1ULL << lane) - 1ULL;
    const int colOff = (tid & 127) << 4;   // 16B column offset within a row
    const int rsel = tid >> 7;             // which of 4 rows in the group
    const char* wbase = (const char*)wrecT;
    const float* rf = (const float*)red4;

    const float* xpp = xproj + (size_t)b * HID + tid;
    float xpn = xpp[0];

    for (int t = 0; t < TSTEPS; ++t) {
        const float xp = xpn;
        if (t + 1 < TSTEPS) xpn = xpp[(size_t)(t + 1) * BATCH * HID];

        // ---- recurrent gather: float4 per thread, 4 rows/group, 8 groups (32 rows)/chunk ----
        float4 acc4 = make_float4(0.f, 0.f, 0.f, 0.f);
        const int* lst = ilist[rb];
        for (int s0 = 0; s0 < cntp; s0 += 32) {
            float4 f[8];
#pragma unroll
            for (int g = 0; g < 8; ++g) {
                const int rr = s0 + 4 * g + rsel;
                const int offr = lst[rr];                       // LDS broadcast (128 thr/addr)
                const unsigned off = (rr < cntp) ? (unsigned)offr : (unsigned)(ZROW << 11);
                f[g] = *reinterpret_cast<const float4*>(wbase + off + colOff);
            }
            __builtin_amdgcn_sched_barrier(0);   // keep the 8 loads in flight before consuming
#pragma unroll
            for (int g = 0; g < 8; ++g) {
                acc4.x += f[g].x; acc4.y += f[g].y;
                acc4.z += f[g].z; acc4.w += f[g].w;
            }
        }
        red4[tid] = acc4;
        __syncthreads();                       // C: red complete (also: ilist[rb] reads done)
        const float r = (rf[tid] + rf[tid + 512]) + (rf[tid + 1024] + rf[tid + 1536]);

        // ---- LIF-AdEx element-wise update ----
        float vd = v + 0.1f * ((((0.f - v) + 0.5f * __expf((v - 1.f) * 2.f)) + cur) - ad);
        float id = cur - 0.2f * cur;
        float aD = ad + 0.002f * (4.f * v - ad);
        bool z = (vd - 1.f) > 0.f;
        v = z ? 0.f : vd;
        cur = id + xp + r;
        ad = aD + (z ? 0.02f : 0.f);
        zf = z ? 1.f : 0.f;

        // ---- build next spike list (exact count, no padding) ----
        unsigned long long m = __ballot(z);
        if (lane == 0) zw[wvi] = m;
        __syncthreads();                       // A: zw visible; red reusable next step
        int off2 = 0, tot = 0;
#pragma unroll
        for (int ww = 0; ww < 8; ++ww) {
            int p = __popcll(zw[ww]);
            if (ww < wvi) off2 += p;
            tot += p;
        }
        const int wb = rb ^ 1;
        if (z) {
            const int p = off2 + __popcll(m & lm);
            ilist[wb][p] = tid << 11;
            glists[((size_t)t * BATCH + b) * HID + p] = (unsigned short)tid;
        }
        if (tid == 0) gcnts[t * BATCH + b] = tot;
        __syncthreads();                       // B: ilist[wb] complete
        cntp = tot;
        rb = wb;
    }

    // final states: z, v, i, a  each [64][512]
    const size_t base = (size_t)b * HID + tid;
    st_out[0 * (size_t)BATCH * HID + base] = zf;
    st_out[1 * (size_t)BATCH * HID + base] = v;
    st_out[2 * (size_t)BATCH * HID + base] = cur;
    st_out[3 * (size_t)BATCH * HID + base] = ad;
}

// ---------------- output projection + exponential filter ----------------
// 16 t-chunks x 64 batch = 1024 blocks; 48-step halo (0.7769^48 ~ 5.5e-6).
// Lists are exact-count now: tail indices masked to ZROW in-register.
__global__ __launch_bounds__(128) void out_kernel(const unsigned short* __restrict__ lists,
                                                  const int* __restrict__ cnts,
                                                  const float* __restrict__ woutT,  // [513][128]
                                                  const float* __restrict__ b_out,
                                                  float* __restrict__ out) {
    const int bid = blockIdx.x;
    const int b = bid & 63;
    const int chunk = bid >> 6;            // 0..15
    const int o = threadIdx.x;
    const unsigned o4 = (unsigned)o << 2;
    const int t0 = chunk * 32;
    const int tstart = (t0 >= 48) ? (t0 - 48) : 0;
    int tend = t0 + 32; if (tend > TSTEPS) tend = TSTEPS;
    const float bo = b_out[o];
    const float cf = 0.2231435511314f;
    const char* wbase = (const char*)woutT;
    float y = 0.f;
    for (int t = tstart; t < tend; ++t) {
        const int cnt = cnts[t * BATCH + b];           // exact count
        const unsigned short* lp = lists + ((size_t)t * BATCH + b) * HID;
        float lin = bo;
        for (int s0 = 0; s0 < cnt; s0 += 32) {
            uint4 u[4];
#pragma unroll
            for (int q = 0; q < 4; ++q) u[q] = *reinterpret_cast<const uint4*>(lp + s0 + 8 * q);
            float f[32];
#pragma unroll
            for (int q = 0; q < 4; ++q) {
                const int e = s0 + 8 * q;
                unsigned a0 = u[q].x, a1 = u[q].y, a2 = u[q].z, a3 = u[q].w;
                unsigned r0 = (e + 0 < cnt) ? (a0 & 0xffffu) : (unsigned)ZROW;
                unsigned r1 = (e + 1 < cnt) ? (a0 >> 16)     : (unsigned)ZROW;
                unsigned r2 = (e + 2 < cnt) ? (a1 & 0xffffu) : (unsigned)ZROW;
                unsigned r3 = (e + 3 < cnt) ? (a1 >> 16)     : (unsigned)ZROW;
                unsigned r4 = (e + 4 < cnt) ? (a2 & 0xffffu) : (unsigned)ZROW;
                unsigned r5 = (e + 5 < cnt) ? (a2 >> 16)     : (unsigned)ZROW;
                unsigned r6 = (e + 6 < cnt) ? (a3 & 0xffffu) : (unsigned)ZROW;
                unsigned r7 = (e + 7 < cnt) ? (a3 >> 16)     : (unsigned)ZROW;
                f[8*q+0] = *reinterpret_cast<const float*>(wbase + (r0 << 9) + o4);
                f[8*q+1] = *reinterpret_cast<const float*>(wbase + (r1 << 9) + o4);
                f[8*q+2] = *reinterpret_cast<const float*>(wbase + (r2 << 9) + o4);
                f[8*q+3] = *reinterpret_cast<const float*>(wbase + (r3 << 9) + o4);
                f[8*q+4] = *reinterpret_cast<const float*>(wbase + (r4 << 9) + o4);
                f[8*q+5] = *reinterpret_cast<const float*>(wbase + (r5 << 9) + o4);
                f[8*q+6] = *reinterpret_cast<const float*>(wbase + (r6 << 9) + o4);
                f[8*q+7] = *reinterpret_cast<const float*>(wbase + (r7 << 9) + o4);
            }
            __builtin_amdgcn_sched_barrier(0);
            float A = 0.f, Bs = 0.f, C = 0.f, D = 0.f;
#pragma unroll
            for (int j = 0; j < 32; j += 4) { A += f[j]; Bs += f[j+1]; C += f[j+2]; D += f[j+3]; }
            lin += (A + Bs) + (C + D);
        }
        y = y + cf * (lin - y);
        if (t >= t0) out[((size_t)t * BATCH + b) * OUTD + o] = y;
    }
}

// ---------------- launcher ----------------
extern "C" void kernel_launch(void* const* d_in, const int* in_sizes, int n_in,
                              void* d_out, int out_size, void* d_ws, size_t ws_size,
                              hipStream_t stream) {
    const float* x     = (const float*)d_in[0];
    const float* w_in  = (const float*)d_in[1];
    const float* w_rec = (const float*)d_in[2];
    const float* w_out = (const float*)d_in[3];
    const float* b_out = (const float*)d_in[4];
    float* out = (float*)d_out;

    char* ws = (char*)d_ws;
    float* xproj          = (float*)(ws + XPROJ_OFF);
    float* wrecT          = (float*)(ws + WRECT_OFF);
    float* woutT          = (float*)(ws + WOUTT_OFF);
    unsigned short* lists = (unsigned short*)(ws + LISTS_OFF);
    int* cnts             = (int*)(ws + CNTS_OFF);
    float* st_out = out + (size_t)TSTEPS * BATCH * OUTD;

    prep_kernel<<<321, 256, 0, stream>>>(w_rec, w_out, wrecT, woutT);
    xproj_kernel<<<1000, 256, 0, stream>>>(x, w_in, xproj);
    scan_kernel<<<64, 512, 0, stream>>>(xproj, wrecT, lists, cnts, st_out);
    out_kernel<<<1024, 128, 0, stream>>>(lists, cnts, woutT, b_out, out);
}

// Round 11
// 833.981 us; speedup vs baseline: 1.4979x; 1.0532x over previous
//
#include <hip/hip_runtime.h>
#include <cstdint>
#include <cstddef>

#define TSTEPS 500
#define BATCH  64
#define FEAT   256
#define HID    512
#define OUTD   128
#define ZROW   512   // all-zero padding row in wrecT/woutT

// ---------------- workspace layout (bytes) ----------------
#define XPROJ_OFF   ((size_t)0)
#define XPROJ_BYTES ((size_t)TSTEPS*BATCH*HID*4)
#define WRECT_OFF   (XPROJ_OFF + XPROJ_BYTES)
#define WRECT_BYTES ((size_t)(HID+1)*HID*4)
#define WOUTT_OFF   (WRECT_OFF + WRECT_BYTES)
#define WOUTT_BYTES ((size_t)(HID+1)*OUTD*4)
#define LISTS_OFF   (WOUTT_OFF + WOUTT_BYTES)
#define LISTS_BYTES ((size_t)TSTEPS*BATCH*HID*2)
#define CNTS_OFF    (LISTS_OFF + LISTS_BYTES)
#define CNTS_BYTES  ((size_t)TSTEPS*BATCH*4)

// ---------------- prep: transposes + zero pad rows ----------------
__global__ __launch_bounds__(256) void prep_kernel(const float* __restrict__ w_rec,
                                                   const float* __restrict__ w_out,
                                                   float* __restrict__ w_recT,
                                                   float* __restrict__ w_outT) {
    __shared__ float tile[32][33];
    int bid = blockIdx.x;
    const int tid = threadIdx.x;

    if (bid == 320) {                 // zero padding rows
        for (int i = tid; i < HID; i += 256) w_recT[(size_t)ZROW * HID + i] = 0.f;
        if (tid < OUTD) w_outT[(size_t)ZROW * OUTD + tid] = 0.f;
        return;
    }

    const float* src;
    float* dst;
    int scols, srows, tr, tc;
    if (bid < 256) {                  // w_rec: 512x512
        src = w_rec; dst = w_recT; srows = 512; scols = 512;
        tr = bid >> 4; tc = bid & 15;
    } else {                          // w_out: 128x512
        bid -= 256;
        src = w_out; dst = w_outT; srows = 128; scols = 512;
        tr = bid >> 4; tc = bid & 15;
    }
    const int c = tid & 31;
    const int r0 = tid >> 5;
#pragma unroll
    for (int p = 0; p < 4; ++p) {
        int r = p * 8 + r0;
        tile[r][c] = src[(size_t)(tr * 32 + r) * scols + tc * 32 + c];
    }
    __syncthreads();
#pragma unroll
    for (int p = 0; p < 4; ++p) {
        int r = p * 8 + r0;
        dst[(size_t)(tc * 32 + r) * srows + tr * 32 + c] = tile[c][r];
    }
}

// ---------------- x_proj GEMM: [32000x256] * [512x256]^T -> [32000x512] fp32 ----------------
// Exact fp32 (r10 lesson: split-bf16 hh+hl+lh leaves ~1e-5 xp error -> spike-flip
// cascade -> absmax 0.166 > 0.159. The SNN is chaotic; xproj must be fp32-exact.)
__global__ __launch_bounds__(256) void xproj_kernel(const float* __restrict__ x,
                                                    const float* __restrict__ w_in,
                                                    float* __restrict__ xp) {
    __shared__ float At[32][132];
    __shared__ float Bt[32][132];
    const int tid = threadIdx.x;
    const int bm = blockIdx.x % 250;
    const int bn = blockIdx.x / 250;
    const int m0 = bm * 128, n0 = bn * 128;
    const int tx = tid & 15, ty = tid >> 4;
    const int lr = tid >> 3;
    const int lc = (tid & 7) << 2;

    float acc[8][8];
#pragma unroll
    for (int i = 0; i < 8; ++i)
#pragma unroll
        for (int j = 0; j < 8; ++j) acc[i][j] = 0.f;

    for (int k0 = 0; k0 < FEAT; k0 += 32) {
#pragma unroll
        for (int rr = 0; rr < 128; rr += 32) {
            float4 av = *reinterpret_cast<const float4*>(x + (size_t)(m0 + lr + rr) * FEAT + k0 + lc);
            At[lc + 0][lr + rr] = av.x; At[lc + 1][lr + rr] = av.y;
            At[lc + 2][lr + rr] = av.z; At[lc + 3][lr + rr] = av.w;
            float4 bv = *reinterpret_cast<const float4*>(w_in + (size_t)(n0 + lr + rr) * FEAT + k0 + lc);
            Bt[lc + 0][lr + rr] = bv.x; Bt[lc + 1][lr + rr] = bv.y;
            Bt[lc + 2][lr + rr] = bv.z; Bt[lc + 3][lr + rr] = bv.w;
        }
        __syncthreads();
#pragma unroll
        for (int kk = 0; kk < 32; ++kk) {
            float a[8], bb[8];
            *reinterpret_cast<float4*>(&a[0]) = *reinterpret_cast<const float4*>(&At[kk][ty * 8]);
            *reinterpret_cast<float4*>(&a[4]) = *reinterpret_cast<const float4*>(&At[kk][ty * 8 + 4]);
            *reinterpret_cast<float4*>(&bb[0]) = *reinterpret_cast<const float4*>(&Bt[kk][tx * 8]);
            *reinterpret_cast<float4*>(&bb[4]) = *reinterpret_cast<const float4*>(&Bt[kk][tx * 8 + 4]);
#pragma unroll
            for (int i = 0; i < 8; ++i)
#pragma unroll
                for (int j = 0; j < 8; ++j)
                    acc[i][j] = fmaf(a[i], bb[j], acc[i][j]);
        }
        __syncthreads();
    }
#pragma unroll
    for (int i = 0; i < 8; ++i) {
        float* dst = xp + (size_t)(m0 + ty * 8 + i) * HID + n0 + tx * 8;
        *reinterpret_cast<float4*>(dst)     = make_float4(acc[i][0], acc[i][1], acc[i][2], acc[i][3]);
        *reinterpret_cast<float4*>(dst + 4) = make_float4(acc[i][4], acc[i][5], acc[i][6], acc[i][7]);
    }
}

// ---------------- recurrent LIF-AdEx scan: one block (512 thr) per batch element ----------------
// Gather: float4/thread, 4 rows/group, 8 groups in flight; granularity-4 tail via
// wave-uniform guard (rsel = tid>>7 is constant within a wave) — no pad-to-32 ZROW waste.
__global__ __launch_bounds__(512)
__attribute__((amdgpu_waves_per_eu(2, 2)))
void scan_kernel(const float* __restrict__ xproj,
                 const float* __restrict__ wrecT,  // [513][512]
                 unsigned short* __restrict__ glists,
                 int* __restrict__ gcnts,
                 float* __restrict__ st_out) {
    const int b = blockIdx.x;
    const int tid = threadIdx.x;           // h
    const int lane = tid & 63;
    const int wvi = tid >> 6;              // 0..7
    __shared__ unsigned long long zw[8];
    __shared__ int ilist[2][HID];
    __shared__ float4 red4[HID];

    float v = 0.f, cur = 0.f, ad = 0.f, zf = 0.f;
    int cntp = 0, rb = 0;
    const unsigned long long lm = (1ULL << lane) - 1ULL;
    const int colOff = (tid & 127) << 4;   // 16B column offset within a row
    const int rsel = tid >> 7;             // which of 4 rows in the group (wave-uniform)
    const char* wbase = (const char*)wrecT;
    const float* rf = (const float*)red4;

    const float* xpp = xproj + (size_t)b * HID + tid;
    float xpn = xpp[0];

    for (int t = 0; t < TSTEPS; ++t) {
        const float xp = xpn;
        if (t + 1 < TSTEPS) xpn = xpp[(size_t)(t + 1) * BATCH * HID];

        // ---- recurrent gather ----
        float4 acc4 = make_float4(0.f, 0.f, 0.f, 0.f);
        const int* lst = ilist[rb];
        const int cnt4 = (cntp + 3) & ~3;
        for (int s0 = 0; s0 < cnt4; s0 += 32) {
            float4 f[8];
#pragma unroll
            for (int g = 0; g < 8; ++g) {
                const int rr = s0 + 4 * g + rsel;
                if (rr < cnt4) {                          // wave-uniform scalar branch
                    f[g] = *reinterpret_cast<const float4*>(wbase + (unsigned)lst[rr] + colOff);
                } else {
                    f[g] = make_float4(0.f, 0.f, 0.f, 0.f);
                }
            }
            __builtin_amdgcn_sched_barrier(0);   // keep valid loads batched in flight
#pragma unroll
            for (int g = 0; g < 8; ++g) {
                acc4.x += f[g].x; acc4.y += f[g].y;
                acc4.z += f[g].z; acc4.w += f[g].w;
            }
        }
        red4[tid] = acc4;
        __syncthreads();                       // C: red complete (ilist[rb] reads done)
        const float r = (rf[tid] + rf[tid + 512]) + (rf[tid + 1024] + rf[tid + 1536]);

        // ---- LIF-AdEx element-wise update ----
        float vd = v + 0.1f * ((((0.f - v) + 0.5f * __expf((v - 1.f) * 2.f)) + cur) - ad);
        float id = cur - 0.2f * cur;
        float aD = ad + 0.002f * (4.f * v - ad);
        bool z = (vd - 1.f) > 0.f;
        v = z ? 0.f : vd;
        cur = id + xp + r;
        ad = aD + (z ? 0.02f : 0.f);
        zf = z ? 1.f : 0.f;

        // ---- build next spike list (exact count; pad only to x4 with ZROW) ----
        unsigned long long m = __ballot(z);
        if (lane == 0) zw[wvi] = m;
        __syncthreads();                       // A: zw visible
        int off2 = 0, tot = 0;
#pragma unroll
        for (int ww = 0; ww < 8; ++ww) {
            int p = __popcll(zw[ww]);
            if (ww < wvi) off2 += p;
            tot += p;
        }
        const int wb = rb ^ 1;
        if (z) {
            const int p = off2 + __popcll(m & lm);
            ilist[wb][p] = tid << 11;
            glists[((size_t)t * BATCH + b) * HID + p] = (unsigned short)tid;
        }
        if (tid >= tot && tid < ((tot + 3) & ~3)) ilist[wb][tid] = ZROW << 11;
        if (tid == 0) gcnts[t * BATCH + b] = tot;
        __syncthreads();                       // B: ilist[wb] complete
        cntp = tot;
        rb = wb;
    }

    // final states: z, v, i, a  each [64][512]
    const size_t base = (size_t)b * HID + tid;
    st_out[0 * (size_t)BATCH * HID + base] = zf;
    st_out[1 * (size_t)BATCH * HID + base] = v;
    st_out[2 * (size_t)BATCH * HID + base] = cur;
    st_out[3 * (size_t)BATCH * HID + base] = ad;
}

// ---------------- output projection + exponential filter ----------------
// 16 t-chunks x 64 batch = 1024 blocks; 48-step halo (0.7769^48 ~ 5.5e-6).
__global__ __launch_bounds__(128) void out_kernel(const unsigned short* __restrict__ lists,
                                                  const int* __restrict__ cnts,
                                                  const float* __restrict__ woutT,  // [513][128]
                                                  const float* __restrict__ b_out,
                                                  float* __restrict__ out) {
    const int bid = blockIdx.x;
    const int b = bid & 63;
    const int chunk = bid >> 6;            // 0..15
    const int o = threadIdx.x;
    const unsigned o4 = (unsigned)o << 2;
    const int t0 = chunk * 32;
    const int tstart = (t0 >= 48) ? (t0 - 48) : 0;
    int tend = t0 + 32; if (tend > TSTEPS) tend = TSTEPS;
    const float bo = b_out[o];
    const float cf = 0.2231435511314f;
    const char* wbase = (const char*)woutT;
    float y = 0.f;
    for (int t = tstart; t < tend; ++t) {
        const int cnt = cnts[t * BATCH + b];           // exact count
        const unsigned short* lp = lists + ((size_t)t * BATCH + b) * HID;
        float lin = bo;
        for (int s0 = 0; s0 < cnt; s0 += 32) {
            uint4 u[4];
#pragma unroll
            for (int q = 0; q < 4; ++q) u[q] = *reinterpret_cast<const uint4*>(lp + s0 + 8 * q);
            float f[32];
#pragma unroll
            for (int q = 0; q < 4; ++q) {
                const int e = s0 + 8 * q;
                unsigned a0 = u[q].x, a1 = u[q].y, a2 = u[q].z, a3 = u[q].w;
                unsigned r0 = (e + 0 < cnt) ? (a0 & 0xffffu) : (unsigned)ZROW;
                unsigned r1 = (e + 1 < cnt) ? (a0 >> 16)     : (unsigned)ZROW;
                unsigned r2 = (e + 2 < cnt) ? (a1 & 0xffffu) : (unsigned)ZROW;
                unsigned r3 = (e + 3 < cnt) ? (a1 >> 16)     : (unsigned)ZROW;
                unsigned r4 = (e + 4 < cnt) ? (a2 & 0xffffu) : (unsigned)ZROW;
                unsigned r5 = (e + 5 < cnt) ? (a2 >> 16)     : (unsigned)ZROW;
                unsigned r6 = (e + 6 < cnt) ? (a3 & 0xffffu) : (unsigned)ZROW;
                unsigned r7 = (e + 7 < cnt) ? (a3 >> 16)     : (unsigned)ZROW;
                f[8*q+0] = *reinterpret_cast<const float*>(wbase + (r0 << 9) + o4);
                f[8*q+1] = *reinterpret_cast<const float*>(wbase + (r1 << 9) + o4);
                f[8*q+2] = *reinterpret_cast<const float*>(wbase + (r2 << 9) + o4);
                f[8*q+3] = *reinterpret_cast<const float*>(wbase + (r3 << 9) + o4);
                f[8*q+4] = *reinterpret_cast<const float*>(wbase + (r4 << 9) + o4);
                f[8*q+5] = *reinterpret_cast<const float*>(wbase + (r5 << 9) + o4);
                f[8*q+6] = *reinterpret_cast<const float*>(wbase + (r6 << 9) + o4);
                f[8*q+7] = *reinterpret_cast<const float*>(wbase + (r7 << 9) + o4);
            }
            __builtin_amdgcn_sched_barrier(0);
            float A = 0.f, Bs = 0.f, C = 0.f, D = 0.f;
#pragma unroll
            for (int j = 0; j < 32; j += 4) { A += f[j]; Bs += f[j+1]; C += f[j+2]; D += f[j+3]; }
            lin += (A + Bs) + (C + D);
        }
        y = y + cf * (lin - y);
        if (t >= t0) out[((size_t)t * BATCH + b) * OUTD + o] = y;
    }
}

// ---------------- launcher ----------------
extern "C" void kernel_launch(void* const* d_in, const int* in_sizes, int n_in,
                              void* d_out, int out_size, void* d_ws, size_t ws_size,
                              hipStream_t stream) {
    const float* x     = (const float*)d_in[0];
    const float* w_in  = (const float*)d_in[1];
    const float* w_rec = (const float*)d_in[2];
    const float* w_out = (const float*)d_in[3];
    const float* b_out = (const float*)d_in[4];
    float* out = (float*)d_out;

    char* ws = (char*)d_ws;
    float* xproj          = (float*)(ws + XPROJ_OFF);
    float* wrecT          = (float*)(ws + WRECT_OFF);
    float* woutT          = (float*)(ws + WOUTT_OFF);
    unsigned short* lists = (unsigned short*)(ws + LISTS_OFF);
    int* cnts             = (int*)(ws + CNTS_OFF);
    float* st_out = out + (size_t)TSTEPS * BATCH * OUTD;

    prep_kernel<<<321, 256, 0, stream>>>(w_rec, w_out, wrecT, woutT);
    xproj_kernel<<<1000, 256, 0, stream>>>(x, w_in, xproj);
    scan_kernel<<<64, 512, 0, stream>>>(xproj, wrecT, lists, cnts, st_out);
    out_kernel<<<1024, 128, 0, stream>>>(lists, cnts, woutT, b_out, out);
}